// Round 12
// baseline (336.715 us; speedup 1.0000x reference)
//
#include <hip/hip_runtime.h>
#include <hip/hip_bf16.h>

#define NN   19
#define DIN  100
#define HID  128
#define TT   250
#define BB   64
#define NC   4
#define FEAT 2432          // NN*HID

typedef __attribute__((ext_vector_type(8))) short s8v;
typedef __attribute__((ext_vector_type(4))) float f4v;
typedef _Float16 h8v __attribute__((ext_vector_type(8)));
typedef _Float16 h4v __attribute__((ext_vector_type(4)));

// =============== V2 workspace layout (byte offsets) ===============
// BFI: W_ih MFMA B-frags f16  (19*8*4*4*512 halfs; per node 65536 halfs)
// BFH: W_hh MFMA B-frags f16  (same count)
// BIAS: combined b_ih+b_hh f32 (19*512)
// W1T: W1 transposed f32 (2432*128) ; HF: final hidden f32 (64*2432)
#define BFI_USH   1245184
#define V2_OFF_BFI  0ull
#define V2_OFF_BFH  2490368ull
#define V2_OFF_BIAS 4980736ull
#define V2_OFF_W1T  5019648ull
#define V2_OFF_HF   6264832ull
#define V2_NEED     6887424ull
#define PACK2_TOTAL (2*BFI_USH + 19*512 + FEAT*HID)

// =============== fallback (round-3) layout, float offsets =========
#define SZ_BF   (NN*8*4*8*512)
#define OFF_W1T_O (SZ_BF/2)
#define SZ_W1T  (FEAT*HID)
#define OFF_HF_O  (OFF_W1T_O + SZ_W1T)
#define PACK_TOTAL_O (SZ_BF + SZ_W1T)

__device__ __forceinline__ unsigned short f2bf(float x) {
    union { float f; unsigned u; } v; v.f = x;
    unsigned r = v.u + 0x7FFF + ((v.u >> 16) & 1);   // RNE
    return (unsigned short)(r >> 16);
}
#define LOG2E 1.4426950408889634f
__device__ __forceinline__ float sigf(float x) {
    return __builtin_amdgcn_rcpf(1.f + __builtin_amdgcn_exp2f(-LOG2E * x));
}
__device__ __forceinline__ float tnhf(float x) {
    return 1.f - 2.f * __builtin_amdgcn_rcpf(__builtin_amdgcn_exp2f(2.f * LOG2E * x) + 1.f);
}

// lgkm-only barrier: LDS ordered; global loads/stores stay in flight.
__device__ __forceinline__ void lgkm_barrier() {
    asm volatile("s_waitcnt lgkmcnt(0)" ::: "memory");
    __builtin_amdgcn_s_barrier();
    asm volatile("" ::: "memory");
}

// ======================= V2 kernels ===============================

// Pack W_ih frags, W_hh frags (f16), combined bias, W1T.
// Frag element (n, hb, nt, kt, lane, e) = W[k][g]:
// k = kt*32+(lane>>4)*8+e, g = nt*128+hb*16+(lane&15).
__global__ __launch_bounds__(256) void pack2_kernel(
        const float* __restrict__ W_ih, const float* __restrict__ W_hh,
        const float* __restrict__ b_ih, const float* __restrict__ b_hh,
        const float* __restrict__ W1, char* __restrict__ wsb) {
    int id = blockIdx.x * 256 + threadIdx.x;
    if (id < 2 * BFI_USH) {
        int which = id >= BFI_USH;                 // 0 = W_ih, 1 = W_hh
        int i = which ? id - BFI_USH : id;
        int e    = i & 7;
        int lane = (i >> 3) & 63;
        int kt   = (i >> 9) & 3;
        int nt   = (i >> 11) & 3;
        int hb   = (i >> 13) & 7;
        int n    = i >> 16;
        int k = kt * 32 + (lane >> 4) * 8 + e;
        int g = nt * 128 + hb * 16 + (lane & 15);
        float v;
        if (which) v = W_hh[((size_t)n * 512 + g) * HID + k];
        else       v = (k < DIN) ? W_ih[((size_t)n * 512 + g) * DIN + k] : 0.f;
        reinterpret_cast<_Float16*>(wsb)[id] = (_Float16)v;
        return;
    }
    int id2 = id - 2 * BFI_USH;
    if (id2 < NN * 512) {
        reinterpret_cast<float*>(wsb + V2_OFF_BIAS)[id2] = b_ih[id2] + b_hh[id2];
        return;
    }
    int id3 = id2 - NN * 512;
    if (id3 < FEAT * HID) {
        int j = id3 & 127, k = id3 >> 7;
        reinterpret_cast<float*>(wsb + V2_OFF_W1T)[id3] = W1[(size_t)j * FEAT + k];
    }
}

// Fused recurrence v9 (split-pipeline): grid 152 = (n, batch-octet),
// 512 thr = 8 waves, wave hb owns 16 hidden j.
//  - W_hh frags in regs; W_ih frags in LDS (128 KB, loaded once)
//  - x and h in SEPARATE double buffers (4 KB each)
//  - entering step t, accC = bias + xpart(t)  (computed at end of t-1)
//  - step t: h-MFMA(t) -> nonlin -> h-write   [the only serial part]
//            then x-stage(t+2) and x-MFMA(t+1) into accN fill the slack
//  - ONE lgkm-only barrier per step
// Tile map: tile row g4*4+q (q=0,1) holds real octet row
// R=(g4&1)*4+(g4>>1)*2+q; other rows stay zero.
__global__ __launch_bounds__(512, 2) void lstm9_kernel(
        const char* __restrict__ wsb, const float* __restrict__ inp,
        float* __restrict__ hf) {
    __shared__ alignas(16) _Float16 wih[8 * 16 * 512];   // 128 KB
    __shared__ alignas(16) _Float16 xbuf[2][16 * 128];   // 2 x 4 KB
    __shared__ alignas(16) _Float16 hbuf[2][16 * 128];   // 2 x 4 KB

    const int tid  = threadIdx.x;
    const int lane = tid & 63;
    const int w8   = tid >> 6;          // 0..7
    const int l15  = lane & 15;
    const int g4   = lane >> 4;
    const int n    = blockIdx.x >> 3;
    const int oct  = blockIdx.x & 7;
    const int bq   = oct >> 1;
    const int hi   = oct & 1;
    const int hb   = w8;
    const int j    = hb * 16 + l15;

    // W_hh frags in regs (16 h8v = 64 regs)
    h8v bf[4][4];
    {
        const _Float16* wp = reinterpret_cast<const _Float16*>(wsb + V2_OFF_BFH)
                             + (size_t)lane * 8;
        #pragma unroll
        for (int nt = 0; nt < 4; ++nt)
            #pragma unroll
            for (int kt = 0; kt < 4; ++kt)
                bf[nt][kt] = *reinterpret_cast<const h8v*>(
                    wp + ((size_t)((n * 8 + hb) * 16 + nt * 4 + kt)) * 512);
    }
    float bs[4];
    #pragma unroll
    for (int nt = 0; nt < 4; ++nt)
        bs[nt] = reinterpret_cast<const float*>(wsb + V2_OFF_BIAS)[n * 512 + nt * 128 + j];

    // W_ih frags -> LDS (128 KB, coalesced)
    {
        const h8v* src = reinterpret_cast<const h8v*>(
            reinterpret_cast<const _Float16*>(wsb + V2_OFF_BFI) + (size_t)n * 65536);
        h8v* dst = reinterpret_cast<h8v*>(wih);
        for (int i = tid; i < 8192; i += 512) dst[i] = src[i];
    }
    // zero x/h buffers (dead rows + k>=100 pad must stay 0)
    for (int i = tid; i < 2 * 16 * 128; i += 512) {
        xbuf[0][i & 2047] = (_Float16)0.f;  // i < 2048 -> buf0, else buf1
        // simpler: explicit
    }
    for (int i = tid; i < 16 * 128; i += 512) {
        xbuf[0][i] = (_Float16)0.f; xbuf[1][i] = (_Float16)0.f;
        hbuf[0][i] = (_Float16)0.f; hbuf[1][i] = (_Float16)0.f;
    }

    // x staging: 200 threads, 8 live tile rows x 25 float4
    const bool st = tid < 200;
    const int sr  = st ? tid / 25 : 0;
    const int c4  = st ? tid - sr * 25 : 0;
    const int g4s = sr >> 1, qs = sr & 1;
    const int tr  = g4s * 4 + qs;                         // live tile row
    const int Rr  = (g4s & 1) * 4 + (g4s >> 1) * 2 + qs;  // real octet row
    const float* xb = inp + (size_t)((bq * 16 + hi * 8 + Rr) * NN + n) * (TT * DIN)
                      + c4 * 4;
    const int wofs_x = tr * 256 + ((c4 * 8) ^ ((tr & 7) << 4));

    const int arow = l15 * 256;
    const int aswz = (l15 & 7) << 4;
    const int wr0 = (g4 * 4) * 256 + ((2 * j) ^ (((g4 * 4) & 7) << 4));
    const int wr1 = (g4 * 4 + 1) * 256 + ((2 * j) ^ (((g4 * 4 + 1) & 7) << 4));
    const char* wfb = reinterpret_cast<const char*>(wih) + hb * 16384 + lane * 16;

    float c2[2] = {0.f, 0.f};
    float h2[2] = {0.f, 0.f};

    __syncthreads();    // zero-init + wih staging complete
    if (st) {   // stage x(0) -> xbuf[0], x(1) -> xbuf[1]
        float4 v0 = *reinterpret_cast<const float4*>(xb);
        float4 v1 = *reinterpret_cast<const float4*>(xb + DIN);
        h4v p0 = {(_Float16)v0.x, (_Float16)v0.y, (_Float16)v0.z, (_Float16)v0.w};
        h4v p1 = {(_Float16)v1.x, (_Float16)v1.y, (_Float16)v1.z, (_Float16)v1.w};
        *reinterpret_cast<h4v*>(reinterpret_cast<char*>(xbuf[0]) + wofs_x) = p0;
        *reinterpret_cast<h4v*>(reinterpret_cast<char*>(xbuf[1]) + wofs_x) = p1;
    }
    __syncthreads();

    // prologue: accC = bias + xpart(0)
    f4v accC[4];
    #pragma unroll
    for (int nt = 0; nt < 4; ++nt)
        accC[nt] = (f4v){bs[nt], bs[nt], 0.f, 0.f};
    {
        const char* rcX = reinterpret_cast<const char*>(xbuf[0]);
        h8v ax0 = *reinterpret_cast<const h8v*>(rcX + arow + ((0 * 64 + g4 * 16) ^ aswz));
        h8v ax1 = *reinterpret_cast<const h8v*>(rcX + arow + ((1 * 64 + g4 * 16) ^ aswz));
        h8v ax2 = *reinterpret_cast<const h8v*>(rcX + arow + ((2 * 64 + g4 * 16) ^ aswz));
        h8v ax3 = *reinterpret_cast<const h8v*>(rcX + arow + ((3 * 64 + g4 * 16) ^ aswz));
        #pragma unroll
        for (int nt = 0; nt < 4; ++nt) {
            h8v w0 = *reinterpret_cast<const h8v*>(wfb + (nt * 4 + 0) * 1024);
            h8v w1 = *reinterpret_cast<const h8v*>(wfb + (nt * 4 + 1) * 1024);
            h8v w2 = *reinterpret_cast<const h8v*>(wfb + (nt * 4 + 2) * 1024);
            h8v w3 = *reinterpret_cast<const h8v*>(wfb + (nt * 4 + 3) * 1024);
            accC[nt] = __builtin_amdgcn_mfma_f32_16x16x32_f16(ax0, w0, accC[nt], 0, 0, 0);
            accC[nt] = __builtin_amdgcn_mfma_f32_16x16x32_f16(ax1, w1, accC[nt], 0, 0, 0);
            accC[nt] = __builtin_amdgcn_mfma_f32_16x16x32_f16(ax2, w2, accC[nt], 0, 0, 0);
            accC[nt] = __builtin_amdgcn_mfma_f32_16x16x32_f16(ax3, w3, accC[nt], 0, 0, 0);
        }
    }
    lgkm_barrier();   // xbuf[0] reads done before t=0 overwrites it

    #pragma unroll 2
    for (int t = 0; t < TT; ++t) {
        const char* rcH = reinterpret_cast<const char*>(hbuf[t & 1]);
        char*       wcH = reinterpret_cast<char*>(hbuf[(t + 1) & 1]);
        char*       wcX = reinterpret_cast<char*>(xbuf[t & 1]);        // x(t+2)
        const char* rcX = reinterpret_cast<const char*>(xbuf[(t + 1) & 1]); // x(t+1)

        // issue global load of x(t+2) early
        float4 nxt = make_float4(0.f, 0.f, 0.f, 0.f);
        int t2 = t + 2 < TT ? t + 2 : TT - 1;
        if (st) nxt = *reinterpret_cast<const float4*>(xb + (size_t)t2 * DIN);

        // ---- serial part: h-MFMA(t) on accC, early nonlin ----
        h8v ah0 = *reinterpret_cast<const h8v*>(rcH + arow + ((0 * 64 + g4 * 16) ^ aswz));
        h8v ah1 = *reinterpret_cast<const h8v*>(rcH + arow + ((1 * 64 + g4 * 16) ^ aswz));
        h8v ah2 = *reinterpret_cast<const h8v*>(rcH + arow + ((2 * 64 + g4 * 16) ^ aswz));
        h8v ah3 = *reinterpret_cast<const h8v*>(rcH + arow + ((3 * 64 + g4 * 16) ^ aswz));

        accC[0] = __builtin_amdgcn_mfma_f32_16x16x32_f16(ah0, bf[0][0], accC[0], 0, 0, 0);
        accC[0] = __builtin_amdgcn_mfma_f32_16x16x32_f16(ah1, bf[0][1], accC[0], 0, 0, 0);
        accC[0] = __builtin_amdgcn_mfma_f32_16x16x32_f16(ah2, bf[0][2], accC[0], 0, 0, 0);
        accC[0] = __builtin_amdgcn_mfma_f32_16x16x32_f16(ah3, bf[0][3], accC[0], 0, 0, 0);
        float ii0 = sigf(accC[0][0]);
        float ii1 = sigf(accC[0][1]);

        accC[1] = __builtin_amdgcn_mfma_f32_16x16x32_f16(ah0, bf[1][0], accC[1], 0, 0, 0);
        accC[1] = __builtin_amdgcn_mfma_f32_16x16x32_f16(ah1, bf[1][1], accC[1], 0, 0, 0);
        accC[1] = __builtin_amdgcn_mfma_f32_16x16x32_f16(ah2, bf[1][2], accC[1], 0, 0, 0);
        accC[1] = __builtin_amdgcn_mfma_f32_16x16x32_f16(ah3, bf[1][3], accC[1], 0, 0, 0);
        float ff0 = sigf(accC[1][0]);
        float ff1 = sigf(accC[1][1]);

        accC[2] = __builtin_amdgcn_mfma_f32_16x16x32_f16(ah0, bf[2][0], accC[2], 0, 0, 0);
        accC[2] = __builtin_amdgcn_mfma_f32_16x16x32_f16(ah1, bf[2][1], accC[2], 0, 0, 0);
        accC[2] = __builtin_amdgcn_mfma_f32_16x16x32_f16(ah2, bf[2][2], accC[2], 0, 0, 0);
        accC[2] = __builtin_amdgcn_mfma_f32_16x16x32_f16(ah3, bf[2][3], accC[2], 0, 0, 0);
        float gg0 = tnhf(accC[2][0]);
        float gg1 = tnhf(accC[2][1]);

        accC[3] = __builtin_amdgcn_mfma_f32_16x16x32_f16(ah0, bf[3][0], accC[3], 0, 0, 0);
        accC[3] = __builtin_amdgcn_mfma_f32_16x16x32_f16(ah1, bf[3][1], accC[3], 0, 0, 0);
        accC[3] = __builtin_amdgcn_mfma_f32_16x16x32_f16(ah2, bf[3][2], accC[3], 0, 0, 0);
        accC[3] = __builtin_amdgcn_mfma_f32_16x16x32_f16(ah3, bf[3][3], accC[3], 0, 0, 0);
        float oo0 = sigf(accC[3][0]);
        float oo1 = sigf(accC[3][1]);

        float cn0 = ff0 * c2[0] + ii0 * gg0;
        c2[0] = cn0;
        float hn0 = oo0 * tnhf(cn0);
        h2[0] = hn0;
        *reinterpret_cast<_Float16*>(wcH + wr0) = (_Float16)hn0;

        float cn1 = ff1 * c2[1] + ii1 * gg1;
        c2[1] = cn1;
        float hn1 = oo1 * tnhf(cn1);
        h2[1] = hn1;
        *reinterpret_cast<_Float16*>(wcH + wr1) = (_Float16)hn1;

        // ---- slack-filling part: x-stage(t+2) and x-MFMA(t+1) ----
        if (st) {
            h4v pk = {(_Float16)nxt.x, (_Float16)nxt.y, (_Float16)nxt.z, (_Float16)nxt.w};
            *reinterpret_cast<h4v*>(wcX + wofs_x) = pk;
        }

        f4v accN[4];
        #pragma unroll
        for (int nt = 0; nt < 4; ++nt)
            accN[nt] = (f4v){bs[nt], bs[nt], 0.f, 0.f};

        h8v ax0 = *reinterpret_cast<const h8v*>(rcX + arow + ((0 * 64 + g4 * 16) ^ aswz));
        h8v ax1 = *reinterpret_cast<const h8v*>(rcX + arow + ((1 * 64 + g4 * 16) ^ aswz));
        h8v ax2 = *reinterpret_cast<const h8v*>(rcX + arow + ((2 * 64 + g4 * 16) ^ aswz));
        h8v ax3 = *reinterpret_cast<const h8v*>(rcX + arow + ((3 * 64 + g4 * 16) ^ aswz));
        #pragma unroll
        for (int nt = 0; nt < 4; ++nt) {
            h8v w0 = *reinterpret_cast<const h8v*>(wfb + (nt * 4 + 0) * 1024);
            h8v w1 = *reinterpret_cast<const h8v*>(wfb + (nt * 4 + 1) * 1024);
            h8v w2 = *reinterpret_cast<const h8v*>(wfb + (nt * 4 + 2) * 1024);
            h8v w3 = *reinterpret_cast<const h8v*>(wfb + (nt * 4 + 3) * 1024);
            accN[nt] = __builtin_amdgcn_mfma_f32_16x16x32_f16(ax0, w0, accN[nt], 0, 0, 0);
            accN[nt] = __builtin_amdgcn_mfma_f32_16x16x32_f16(ax1, w1, accN[nt], 0, 0, 0);
            accN[nt] = __builtin_amdgcn_mfma_f32_16x16x32_f16(ax2, w2, accN[nt], 0, 0, 0);
            accN[nt] = __builtin_amdgcn_mfma_f32_16x16x32_f16(ax3, w3, accN[nt], 0, 0, 0);
        }
        #pragma unroll
        for (int nt = 0; nt < 4; ++nt) accC[nt] = accN[nt];

        lgkm_barrier();
    }

    #pragma unroll
    for (int q = 0; q < 2; ++q) {
        int b = bq * 16 + hi * 8 + (g4 & 1) * 4 + (g4 >> 1) * 2 + q;
        hf[((size_t)b * NN + n) * HID + j] = h2[q];
    }
}

// Head: 64 blocks (one per batch row), 256 thr, split-K over 2 halves.
__global__ __launch_bounds__(256) void head2_kernel(
        const float* __restrict__ hf, const float* __restrict__ w1t,
        const float* __restrict__ b1, const float* __restrict__ W2,
        const float* __restrict__ b2, float* __restrict__ out) {
    __shared__ float comb[FEAT];
    __shared__ float par[2][HID];
    __shared__ float hid[HID];
    const int b = blockIdx.x;
    const int u  = threadIdx.x & 127;
    const int kk = threadIdx.x >> 7;
    const float* hfp = hf + (size_t)b * FEAT;
    for (int i = threadIdx.x; i < FEAT; i += 256) comb[i] = hfp[i];
    __syncthreads();

    const int k0 = kk * (FEAT / 2);
    float acc = 0.f;
    #pragma unroll 8
    for (int k = 0; k < FEAT / 2; ++k)
        acc = fmaf(comb[k0 + k], w1t[(size_t)(k0 + k) * HID + u], acc);
    par[kk][u] = acc;
    __syncthreads();
    if (kk == 0) hid[u] = fmaxf(par[0][u] + par[1][u] + b1[u], 0.f);
    __syncthreads();

    if (threadIdx.x < NC) {
        int cls = threadIdx.x;
        float a = b2[cls];
        #pragma unroll 4
        for (int k = 0; k < HID; ++k)
            a = fmaf(hid[k], W2[cls * HID + k], a);
        out[b * NC + cls] = a;
    }
}

// ======================= fallback (round-3) =======================
__global__ __launch_bounds__(256) void packfb_kernel(
        const float* __restrict__ W_ih, const float* __restrict__ W_hh,
        const float* __restrict__ W1,
        unsigned short* __restrict__ bfw, float* __restrict__ w1t) {
    int id = blockIdx.x * 256 + threadIdx.x;
    if (id < SZ_BF) {
        int e    = id & 7;
        int lane = (id >> 3) & 63;
        int kt   = (id >> 9) & 7;
        int nt   = (id >> 12) & 3;
        int hb   = (id >> 14) & 7;
        int n    = id >> 17;
        int k = kt * 32 + (lane >> 4) * 8 + e;
        int g = nt * 128 + hb * 16 + (lane & 15);
        float v = 0.f;
        if (k < DIN)       v = W_ih[((size_t)n * 512 + g) * DIN + k];
        else if (k < 228)  v = W_hh[((size_t)n * 512 + g) * HID + (k - DIN)];
        bfw[id] = f2bf(v);
        return;
    }
    int id3 = id - SZ_BF;
    if (id3 < SZ_W1T) {
        int j = id3 & 127, k = id3 >> 7;
        w1t[id3] = W1[(size_t)j * FEAT + k];
    }
}

__global__ __launch_bounds__(512, 2) void lstmfb_kernel(
        const float* __restrict__ inp,
        const float* __restrict__ b_ih, const float* __restrict__ b_hh,
        const unsigned short* __restrict__ bfw, float* __restrict__ hf) {
    __shared__ alignas(16) unsigned short xh[2][16 * 256];
    const int tid  = threadIdx.x;
    const int lane = tid & 63;
    const int w    = tid >> 6;
    const int l15  = lane & 15;
    const int g4   = lane >> 4;
    const int n    = blockIdx.x >> 2;
    const int bq   = blockIdx.x & 3;
    const int j    = w * 16 + l15;

    s8v bf[4][8];
    const unsigned short* wp = bfw + ((size_t)(n * 8 + w) * 32) * 512 + lane * 8;
    #pragma unroll
    for (int nt = 0; nt < 4; ++nt)
        #pragma unroll
        for (int kt = 0; kt < 8; ++kt)
            bf[nt][kt] = *reinterpret_cast<const s8v*>(wp + (nt * 8 + kt) * 512);

    float bs[4];
    #pragma unroll
    for (int nt = 0; nt < 4; ++nt)
        bs[nt] = b_ih[n * 512 + nt * 128 + j] + b_hh[n * 512 + nt * 128 + j];

    float c[4] = {0.f, 0.f, 0.f, 0.f};
    float h[4] = {0.f, 0.f, 0.f, 0.f};
    for (int i = tid; i < 2 * 16 * 256; i += 512) (&xh[0][0])[i] = 0;

    const bool st = tid < 400;
    const int row = st ? tid / 25 : 0;
    const int c4  = st ? tid - row * 25 : 0;
    const float* xb = inp + ((size_t)(bq * 16 + row) * NN + n) * (TT * DIN) + c4 * 4;
    const int wofs = row * 512 + ((c4 * 8) ^ ((row & 7) << 4));
    const int arow = l15 * 512;
    const int aswz = (l15 & 7) << 4;

    __syncthreads();
    if (st) {
        float4 v = *reinterpret_cast<const float4*>(xb);
        unsigned lo = f2bf(v.x) | ((unsigned)f2bf(v.y) << 16);
        unsigned hi = f2bf(v.z) | ((unsigned)f2bf(v.w) << 16);
        *reinterpret_cast<uint2*>(reinterpret_cast<char*>(xh[0]) + wofs) =
            make_uint2(lo, hi);
    }
    __syncthreads();

    for (int t = 0; t < TT; ++t) {
        char* rc = reinterpret_cast<char*>(xh[t & 1]);
        char* wc = reinterpret_cast<char*>(xh[(t + 1) & 1]);
        float4 nxt = make_float4(0.f, 0.f, 0.f, 0.f);
        if (t < TT - 1 && st)
            nxt = *reinterpret_cast<const float4*>(xb + (t + 1) * DIN);

        f4v acc[4];
        #pragma unroll
        for (int nt = 0; nt < 4; ++nt)
            acc[nt] = (f4v){bs[nt], bs[nt], bs[nt], bs[nt]};
        #pragma unroll
        for (int kt = 0; kt < 8; ++kt) {
            s8v a = *reinterpret_cast<const s8v*>(rc + arow + ((kt * 64 + g4 * 16) ^ aswz));
            #pragma unroll
            for (int nt = 0; nt < 4; ++nt)
                acc[nt] = __builtin_amdgcn_mfma_f32_16x16x32_bf16(a, bf[nt][kt], acc[nt], 0, 0, 0);
        }
        #pragma unroll
        for (int r = 0; r < 4; ++r) {
            float ii = sigf(acc[0][r]);
            float ff = sigf(acc[1][r]);
            float gg = tnhf(acc[2][r]);
            float oo = sigf(acc[3][r]);
            float cn = ff * c[r] + ii * gg;
            c[r] = cn;
            float hn = oo * tnhf(cn);
            h[r] = hn;
            int rr = g4 * 4 + r;
            *reinterpret_cast<unsigned short*>(
                wc + rr * 512 + (((DIN + j) * 2) ^ ((rr & 7) << 4))) = f2bf(hn);
        }
        if (t < TT - 1 && st) {
            unsigned lo = f2bf(nxt.x) | ((unsigned)f2bf(nxt.y) << 16);
            unsigned hi = f2bf(nxt.z) | ((unsigned)f2bf(nxt.w) << 16);
            *reinterpret_cast<uint2*>(wc + wofs) = make_uint2(lo, hi);
        }
        __syncthreads();
    }
    #pragma unroll
    for (int r = 0; r < 4; ++r) {
        int b = bq * 16 + g4 * 4 + r;
        hf[((size_t)b * NN + n) * HID + j] = h[r];
    }
}

// ============================ launch ==============================
extern "C" void kernel_launch(void* const* d_in, const int* in_sizes, int n_in,
                              void* d_out, int out_size, void* d_ws, size_t ws_size,
                              hipStream_t stream) {
    const float* inp  = (const float*)d_in[0];
    const float* W_ih = (const float*)d_in[2];
    const float* W_hh = (const float*)d_in[3];
    const float* b_ih = (const float*)d_in[4];
    const float* b_hh = (const float*)d_in[5];
    const float* W1   = (const float*)d_in[6];
    const float* b1   = (const float*)d_in[7];
    const float* W2   = (const float*)d_in[8];
    const float* b2   = (const float*)d_in[9];
    float* out = (float*)d_out;

    if (ws_size >= V2_NEED) {
        char* wsb = (char*)d_ws;
        float* hf  = (float*)(wsb + V2_OFF_HF);
        float* w1t = (float*)(wsb + V2_OFF_W1T);
        pack2_kernel<<<(PACK2_TOTAL + 255) / 256, 256, 0, stream>>>(
            W_ih, W_hh, b_ih, b_hh, W1, wsb);
        lstm9_kernel<<<NN * 8, 512, 0, stream>>>(wsb, inp, hf);
        head2_kernel<<<BB, 256, 0, stream>>>(hf, w1t, b1, W2, b2, out);
    } else {
        float* ws = (float*)d_ws;
        unsigned short* bfw = (unsigned short*)d_ws;
        packfb_kernel<<<(PACK_TOTAL_O + 255) / 256, 256, 0, stream>>>(
            W_ih, W_hh, W1, bfw, ws + OFF_W1T_O);
        lstmfb_kernel<<<NN * 4, 512, 0, stream>>>(inp, b_ih, b_hh, bfw, ws + OFF_HF_O);
        head2_kernel<<<BB, 256, 0, stream>>>(ws + OFF_HF_O, ws + OFF_W1T_O,
                                             b1, W2, b2, out);
    }
}